// Round 2
// baseline (222.708 us; speedup 1.0000x reference)
//
#include <hip/hip_runtime.h>

// Fused single-kernel GEMV chain for the DCE'd MHA (kv_len==1 => softmax==1):
//   v    = v_w  @ text + v_b              (2048 x 4096, 32 MB)
//   ctx  = wv   @ v    + bv               (2048 x 2048, 16 MB)  wv = in_w rows 4096..6143
//   attn = mo_w @ ctx  + mo_b             (2048 x 2048, 16 MB)
//   out  = visual + o_w @ attn + o_b      (4096 x 2048, 32 MB)
//
// Round-1 post-mortem (250 us, VALUBusy 0.8%, VGPR=44):
//  (a) relaxed AGENT-scope poll load was served from the stale per-XCD L2 ->
//      ~80 us of dead spin per barrier until incidental eviction. FIX: poll and
//      release at SYSTEM scope (sc0 sc1 -> reads coherence point every poll),
//      plus a periodic __threadfence fallback so worst case is us-scale.
//  (b) VGPR=44 proves the compiler sank the "prefetched" weight loads below the
//      barriers -- the registers never held them. FIX: pin every prefetched
//      component with asm volatile("" : "+v"(x)) before barrier_wait; an
//      inline-asm def cannot be rematerialized, so loads stay above the spin.
//
// Residency: __launch_bounds__(256,4) caps VGPR at 128 -> 4 blocks/CU is a
// register-file certainty; grid = 1024 = 256 CU x 4, all blocks co-resident
// (empirically confirmed in round 1: barrier completed, kernel passed).

#define ED 2048
#define VD 4096
#define NB 1024
#define NT 256

__device__ __forceinline__ float wave_red(float v) {
#pragma unroll
    for (int off = 32; off > 0; off >>= 1) v += __shfl_down(v, off, 64);
    return v;
}

__device__ __forceinline__ void pin4(float4& v) {
    asm volatile("" : "+v"(v.x), "+v"(v.y), "+v"(v.z), "+v"(v.w));
}

__device__ __forceinline__ void barrier_arrive(unsigned* base, int b) {
    if (threadIdx.x == 0) {
        __threadfence();   // release: push vvec/ctx/attn stores past local L2
        if (atomicAdd(base + (b >> 5), 1u) == 31u)       // 32 blocks per leaf
            if (atomicAdd(base + 32, 1u) == 31u)         // 32 leaves
                __hip_atomic_store(base + 33, 1u, __ATOMIC_RELAXED,
                                   __HIP_MEMORY_SCOPE_SYSTEM);
    }
}

__device__ __forceinline__ void barrier_wait(unsigned* base) {
    if (threadIdx.x == 0) {
        int spins = 0;
        while (__hip_atomic_load(base + 33, __ATOMIC_RELAXED,
                                 __HIP_MEMORY_SCOPE_SYSTEM) == 0u) {
            __builtin_amdgcn_s_sleep(2);
            ++spins;
            if ((spins & 7) == 0) __threadfence();  // freshness fallback
            if (spins > (1 << 16)) break;           // visible fail, never hang
        }
        __threadfence();   // acquire: invalidate L1/L2 so x-reads are fresh
    }
    __syncthreads();
}

__global__ __launch_bounds__(NT, 4)
void fused_chain(const float* __restrict__ visual,
                 const float* __restrict__ text,
                 const float* __restrict__ v_w,  const float* __restrict__ v_b,
                 const float* __restrict__ wv,   const float* __restrict__ bv,
                 const float* __restrict__ mo_w, const float* __restrict__ mo_b,
                 const float* __restrict__ o_w,  const float* __restrict__ o_b,
                 float* __restrict__ vvec, float* __restrict__ ctx,
                 float* __restrict__ attn, unsigned* __restrict__ flags,
                 float* __restrict__ out)
{
    const int t    = threadIdx.x;
    const int b    = blockIdx.x;
    const int lane = t & 63;
    const int wid  = t >> 6;
    __shared__ float lds[16];

    const int r2 = 2 * b;   // row pair for stages 1-3
    const int r4 = 4 * b;   // row quad for stage 4

    // ---- tiny prefetch: biases + residual (t0 only) ----
    float bi10 = 0.f, bi11 = 0.f, bi20 = 0.f, bi21 = 0.f, bi30 = 0.f, bi31 = 0.f;
    float bo0 = 0.f, bo1 = 0.f, bo2 = 0.f, bo3 = 0.f;
    float rv0 = 0.f, rv1 = 0.f, rv2 = 0.f, rv3 = 0.f;
    if (t == 0) {
        bi10 = v_b[r2];   bi11 = v_b[r2 + 1];
        bi20 = bv[r2];    bi21 = bv[r2 + 1];
        bi30 = mo_b[r2];  bi31 = mo_b[r2 + 1];
        bo0 = o_b[r4];    bo1 = o_b[r4 + 1];  bo2 = o_b[r4 + 2];  bo3 = o_b[r4 + 3];
        rv0 = visual[r4]; rv1 = visual[r4+1]; rv2 = visual[r4+2]; rv3 = visual[r4+3];
    }

    // ---- stage-1 loads (W1: 2 rows x 4 f4, x1: 4 f4) + W2 prefetch ----
    const float4* w1a = (const float4*)(v_w + (size_t)r2 * VD);
    const float4* w1b = (const float4*)(v_w + (size_t)(r2 + 1) * VD);
    const float4* x1p = (const float4*)text;
    float4 w10[4], w11[4], x1[4];
#pragma unroll
    for (int j = 0; j < 4; ++j) w10[j] = w1a[t + j * NT];
#pragma unroll
    for (int j = 0; j < 4; ++j) w11[j] = w1b[t + j * NT];
#pragma unroll
    for (int j = 0; j < 4; ++j) x1[j]  = x1p[t + j * NT];

    const float4* w2a = (const float4*)(wv + (size_t)r2 * ED);
    const float4* w2b = (const float4*)(wv + (size_t)(r2 + 1) * ED);
    float4 w20[2], w21[2];
#pragma unroll
    for (int j = 0; j < 2; ++j) w20[j] = w2a[t + j * NT];
#pragma unroll
    for (int j = 0; j < 2; ++j) w21[j] = w2b[t + j * NT];

    // ---- stage 1: v = v_w @ text + v_b ----
    float a0 = 0.f, a1 = 0.f;
#pragma unroll
    for (int j = 0; j < 4; ++j) {
        a0 = fmaf(w10[j].x, x1[j].x, a0); a0 = fmaf(w10[j].y, x1[j].y, a0);
        a0 = fmaf(w10[j].z, x1[j].z, a0); a0 = fmaf(w10[j].w, x1[j].w, a0);
        a1 = fmaf(w11[j].x, x1[j].x, a1); a1 = fmaf(w11[j].y, x1[j].y, a1);
        a1 = fmaf(w11[j].z, x1[j].z, a1); a1 = fmaf(w11[j].w, x1[j].w, a1);
    }
    a0 = wave_red(a0); a1 = wave_red(a1);
    if (lane == 0) { lds[wid] = a0; lds[4 + wid] = a1; }
    __syncthreads();
    if (t == 0) {
        vvec[r2]     = lds[0] + lds[1] + lds[2] + lds[3] + bi10;
        vvec[r2 + 1] = lds[4] + lds[5] + lds[6] + lds[7] + bi11;
    }
    barrier_arrive(flags, b);

    // ---- W3 prefetch flies while stragglers finish stage 1 + we spin ----
    const float4* w3a = (const float4*)(mo_w + (size_t)r2 * ED);
    const float4* w3b = (const float4*)(mo_w + (size_t)(r2 + 1) * ED);
    float4 w30[2], w31[2];
#pragma unroll
    for (int j = 0; j < 2; ++j) w30[j] = w3a[t + j * NT];
#pragma unroll
    for (int j = 0; j < 2; ++j) w31[j] = w3b[t + j * NT];

    // Pin everything that must survive barrier 1 in registers.
#pragma unroll
    for (int j = 0; j < 2; ++j) { pin4(w20[j]); pin4(w21[j]); pin4(w30[j]); pin4(w31[j]); }

    barrier_wait(flags);

    // ---- stage 2: ctx = wv @ v + bv (weights already in registers) ----
    const float4* xvp = (const float4*)vvec;
    float4 x2[2];
#pragma unroll
    for (int j = 0; j < 2; ++j) x2[j] = xvp[t + j * NT];
    a0 = 0.f; a1 = 0.f;
#pragma unroll
    for (int j = 0; j < 2; ++j) {
        a0 = fmaf(w20[j].x, x2[j].x, a0); a0 = fmaf(w20[j].y, x2[j].y, a0);
        a0 = fmaf(w20[j].z, x2[j].z, a0); a0 = fmaf(w20[j].w, x2[j].w, a0);
        a1 = fmaf(w21[j].x, x2[j].x, a1); a1 = fmaf(w21[j].y, x2[j].y, a1);
        a1 = fmaf(w21[j].z, x2[j].z, a1); a1 = fmaf(w21[j].w, x2[j].w, a1);
    }
    a0 = wave_red(a0); a1 = wave_red(a1);
    if (lane == 0) { lds[wid] = a0; lds[4 + wid] = a1; }
    __syncthreads();
    if (t == 0) {
        ctx[r2]     = lds[0] + lds[1] + lds[2] + lds[3] + bi20;
        ctx[r2 + 1] = lds[4] + lds[5] + lds[6] + lds[7] + bi21;
    }
    barrier_arrive(flags + 64, b);

    // ---- W4 first half (rows r4, r4+1) prefetch across barrier 2 ----
    const float4* w4a = (const float4*)(o_w + (size_t)r4 * ED);
    const float4* w4b = (const float4*)(o_w + (size_t)(r4 + 1) * ED);
    float4 w40[2], w41[2];
#pragma unroll
    for (int j = 0; j < 2; ++j) w40[j] = w4a[t + j * NT];
#pragma unroll
    for (int j = 0; j < 2; ++j) w41[j] = w4b[t + j * NT];

#pragma unroll
    for (int j = 0; j < 2; ++j) { pin4(w30[j]); pin4(w31[j]); pin4(w40[j]); pin4(w41[j]); }

    barrier_wait(flags + 64);

    // ---- stage 3: attn = mo_w @ ctx + mo_b ----
    const float4* xcp = (const float4*)ctx;
    float4 x3[2];
#pragma unroll
    for (int j = 0; j < 2; ++j) x3[j] = xcp[t + j * NT];
    // Pin issue order: x3 first, THEN W4 second half -> x3's vmcnt wait does not
    // trap the W4cd stream; W4cd overlaps stage-3 compute + barrier 3.
    __builtin_amdgcn_sched_barrier(0);
    const float4* w4c = (const float4*)(o_w + (size_t)(r4 + 2) * ED);
    const float4* w4d = (const float4*)(o_w + (size_t)(r4 + 3) * ED);
    float4 w42[2], w43[2];
#pragma unroll
    for (int j = 0; j < 2; ++j) w42[j] = w4c[t + j * NT];
#pragma unroll
    for (int j = 0; j < 2; ++j) w43[j] = w4d[t + j * NT];

    a0 = 0.f; a1 = 0.f;
#pragma unroll
    for (int j = 0; j < 2; ++j) {
        a0 = fmaf(w30[j].x, x3[j].x, a0); a0 = fmaf(w30[j].y, x3[j].y, a0);
        a0 = fmaf(w30[j].z, x3[j].z, a0); a0 = fmaf(w30[j].w, x3[j].w, a0);
        a1 = fmaf(w31[j].x, x3[j].x, a1); a1 = fmaf(w31[j].y, x3[j].y, a1);
        a1 = fmaf(w31[j].z, x3[j].z, a1); a1 = fmaf(w31[j].w, x3[j].w, a1);
    }
    a0 = wave_red(a0); a1 = wave_red(a1);
    if (lane == 0) { lds[wid] = a0; lds[4 + wid] = a1; }
    __syncthreads();
    if (t == 0) {
        attn[r2]     = lds[0] + lds[1] + lds[2] + lds[3] + bi30;
        attn[r2 + 1] = lds[4] + lds[5] + lds[6] + lds[7] + bi31;
    }
    barrier_arrive(flags + 128, b);

#pragma unroll
    for (int j = 0; j < 2; ++j) { pin4(w40[j]); pin4(w41[j]); pin4(w42[j]); pin4(w43[j]); }

    barrier_wait(flags + 128);

    // ---- stage 4: out = visual + o_w @ attn + o_b (4 rows/block) ----
    const float4* xap = (const float4*)attn;
    float4 x4[2];
#pragma unroll
    for (int j = 0; j < 2; ++j) x4[j] = xap[t + j * NT];
    float c0 = 0.f, c1 = 0.f, c2 = 0.f, c3 = 0.f;
#pragma unroll
    for (int j = 0; j < 2; ++j) {
        c0 = fmaf(w40[j].x, x4[j].x, c0); c0 = fmaf(w40[j].y, x4[j].y, c0);
        c0 = fmaf(w40[j].z, x4[j].z, c0); c0 = fmaf(w40[j].w, x4[j].w, c0);
        c1 = fmaf(w41[j].x, x4[j].x, c1); c1 = fmaf(w41[j].y, x4[j].y, c1);
        c1 = fmaf(w41[j].z, x4[j].z, c1); c1 = fmaf(w41[j].w, x4[j].w, c1);
        c2 = fmaf(w42[j].x, x4[j].x, c2); c2 = fmaf(w42[j].y, x4[j].y, c2);
        c2 = fmaf(w42[j].z, x4[j].z, c2); c2 = fmaf(w42[j].w, x4[j].w, c2);
        c3 = fmaf(w43[j].x, x4[j].x, c3); c3 = fmaf(w43[j].y, x4[j].y, c3);
        c3 = fmaf(w43[j].z, x4[j].z, c3); c3 = fmaf(w43[j].w, x4[j].w, c3);
    }
    c0 = wave_red(c0); c1 = wave_red(c1); c2 = wave_red(c2); c3 = wave_red(c3);
    if (lane == 0) {
        lds[wid] = c0; lds[4 + wid] = c1; lds[8 + wid] = c2; lds[12 + wid] = c3;
    }
    __syncthreads();
    if (t == 0) {
        out[r4]     = lds[0]  + lds[1]  + lds[2]  + lds[3]  + bo0 + rv0;
        out[r4 + 1] = lds[4]  + lds[5]  + lds[6]  + lds[7]  + bo1 + rv1;
        out[r4 + 2] = lds[8]  + lds[9]  + lds[10] + lds[11] + bo2 + rv2;
        out[r4 + 3] = lds[12] + lds[13] + lds[14] + lds[15] + bo3 + rv3;
    }
}

extern "C" void kernel_launch(void* const* d_in, const int* in_sizes, int n_in,
                              void* d_out, int out_size, void* d_ws, size_t ws_size,
                              hipStream_t stream) {
    (void)in_sizes; (void)n_in; (void)out_size; (void)ws_size;
    const float* visual = (const float*)d_in[0];   // [4096]
    const float* text   = (const float*)d_in[1];   // [4096]
    // d_in[2..5] = q_w, q_b, k_w, k_b -> dead (softmax over single key == 1)
    const float* v_w  = (const float*)d_in[6];     // [2048, 4096]
    const float* v_b  = (const float*)d_in[7];     // [2048]
    const float* in_w = (const float*)d_in[8];     // [6144, 2048]
    const float* in_b = (const float*)d_in[9];     // [6144]
    const float* mo_w = (const float*)d_in[10];    // [2048, 2048]
    const float* mo_b = (const float*)d_in[11];    // [2048]
    const float* o_w  = (const float*)d_in[12];    // [4096, 2048]
    const float* o_b  = (const float*)d_in[13];    // [4096]
    float* out = (float*)d_out;                    // [4096]

    const float* wv = in_w + (size_t)2 * ED * ED;  // in_w rows 4096..6143
    const float* bv = in_b + 2 * ED;

    float* ws   = (float*)d_ws;
    float* vvec = ws;               // [2048]
    float* ctx  = ws + ED;          // [2048]
    float* attn = ws + 2 * ED;      // [2048]
    unsigned* flags = (unsigned*)(ws + 8192);   // 3 stages x 64 uints, 32KB offset

    // Workspace is poisoned between iterations -> barrier state must be zeroed.
    hipMemsetAsync(flags, 0, 3 * 64 * sizeof(unsigned), stream);
    fused_chain<<<NB, NT, 0, stream>>>(visual, text, v_w, v_b, wv, bv,
                                       mo_b ? mo_w : mo_w, mo_b, o_w, o_b,
                                       vvec, ctx, attn, flags, out);
}

// Round 3
// 188.944 us; speedup vs baseline: 1.1787x; 1.1787x over previous
//
#include <hip/hip_runtime.h>

// Fused single-kernel GEMV chain for the DCE'd MHA (kv_len==1 => softmax==1):
//   v    = v_w  @ text + v_b              (2048 x 4096, 32 MB)
//   ctx  = wv   @ v    + bv               (2048 x 2048, 16 MB)  wv = in_w rows 4096..6143
//   attn = mo_w @ ctx  + mo_b             (2048 x 2048, 16 MB)
//   out  = visual + o_w @ attn + o_b      (4096 x 2048, 32 MB)
//
// Round-1/2 post-mortem: VGPR_Count=44 both rounds => compiler NEVER held the
// weight operands in registers (stage 1 alone needs 48). Every wave ran a
// serialized load->use chain: 170 GB/s aggregate = ~1.5 outstanding loads/wave.
// The barrier was never the dominant cost; register allocation was.
//
// Round-3 fix: take operands out of VGPRs entirely. global_load_lds has no
// VGPR destination -> cannot be sunk/serialized/spilled. 32 KB/block in flight
// (128 KB/CU) saturates HBM by construction. LDS ping-pong A/B slots; the
// reduce __syncthreads of each stage doubles as the WAR guard before the next
// staging issue; barrier_wait's __syncthreads drains vmcnt before LDS reads.
// Next-stage weights are staged BEFORE the grid-barrier spin -> HBM stays busy
// across stage boundaries (the whole point of fusing).
//
// Barrier: 2-level tree (32 leaves + root), SYSTEM-scope release store and
// poll (round-2 proven correct), one release/acquire __threadfence pair.
// Residency: 1024 blocks = 256 CU x 4; LDS 32.06 KB -> exactly 4 blocks/CU.

#define ED 2048
#define VD 4096
#define NB 1024
#define NT 256

__device__ __forceinline__ float wave_red(float v) {
#pragma unroll
    for (int off = 32; off > 0; off >>= 1) v += __shfl_down(v, off, 64);
    return v;
}

__device__ __forceinline__ void gload_lds16(const float* g, float* l) {
    __builtin_amdgcn_global_load_lds(
        (const __attribute__((address_space(1))) void*)g,
        (__attribute__((address_space(3))) void*)l, 16, 0, 0);
}

// Stage one 16 KB row (4096 floats) into an LDS slot. 16 chunks of 1 KB;
// wave w issues chunks 4w..4w+3. gaddr is per-lane, LDS base wave-uniform.
__device__ __forceinline__ void stage16k(const float* g, float* l, int wid, int lane) {
#pragma unroll
    for (int j = 0; j < 4; ++j) {
        const int c = wid * 4 + j;
        gload_lds16(g + c * 256 + lane * 4, l + c * 256);
    }
}

// Stage one 8 KB row (2048 floats): 8 chunks, wave w issues chunks 2w..2w+1.
__device__ __forceinline__ void stage8k(const float* g, float* l, int wid, int lane) {
#pragma unroll
    for (int j = 0; j < 2; ++j) {
        const int c = wid * 2 + j;
        gload_lds16(g + c * 256 + lane * 4, l + c * 256);
    }
}

__device__ __forceinline__ void barrier_arrive(unsigned* base, int b) {
    if (threadIdx.x == 0) {
        __threadfence();   // release: push vvec/ctx/attn stores to coherence point
        if (atomicAdd(base + (b >> 5), 1u) == 31u)       // 32 blocks per leaf
            if (atomicAdd(base + 32, 1u) == 31u)         // 32 leaves
                __hip_atomic_store(base + 33, 1u, __ATOMIC_RELAXED,
                                   __HIP_MEMORY_SCOPE_SYSTEM);
    }
}

__device__ __forceinline__ void barrier_wait(unsigned* base) {
    if (threadIdx.x == 0) {
        int spins = 0;
        while (__hip_atomic_load(base + 33, __ATOMIC_RELAXED,
                                 __HIP_MEMORY_SCOPE_SYSTEM) == 0u) {
            __builtin_amdgcn_s_sleep(2);
            if (++spins > (1 << 17)) break;   // visible fail, never hang
        }
        __threadfence();   // acquire: L1/L2 inv so x-vector reads are fresh
    }
    __syncthreads();       // also drains vmcnt -> staged LDS data valid
}

__global__ __launch_bounds__(NT, 4)
void fused_chain(const float* __restrict__ visual,
                 const float* __restrict__ text,
                 const float* __restrict__ v_w,  const float* __restrict__ v_b,
                 const float* __restrict__ wv,   const float* __restrict__ bv,
                 const float* __restrict__ mo_w, const float* __restrict__ mo_b,
                 const float* __restrict__ o_w,  const float* __restrict__ o_b,
                 float* __restrict__ vvec, float* __restrict__ ctx,
                 float* __restrict__ attn, unsigned* __restrict__ flags,
                 float* __restrict__ out)
{
    __shared__ __align__(16) float sA[4096];   // 16 KB slot A
    __shared__ __align__(16) float sB[4096];   // 16 KB slot B
    __shared__ float red[16];

    const int t    = threadIdx.x;
    const int b    = blockIdx.x;
    const int lane = t & 63;
    const int wid  = t >> 6;
    const int r2   = 2 * b;   // row pair, stages 1-3
    const int r4   = 4 * b;   // row quad, stage 4

    const float4* A4 = (const float4*)sA;
    const float4* B4 = (const float4*)sB;

    // ---- stage W1 rows -> A,B; x1 -> regs ----
    stage16k(v_w + (size_t)r2 * VD,       sA, wid, lane);
    stage16k(v_w + (size_t)(r2 + 1) * VD, sB, wid, lane);
    const float4* x1p = (const float4*)text;
    float4 x1[4];
#pragma unroll
    for (int j = 0; j < 4; ++j) x1[j] = x1p[t + j * NT];
    __syncthreads();                       // drains vmcnt: LDS + x1 ready

    // ---- stage 1: v = v_w @ text + v_b ----
    float a0 = 0.f, a1 = 0.f;
#pragma unroll
    for (int j = 0; j < 4; ++j) {
        float4 wa = A4[t + j * NT], wb = B4[t + j * NT];
        a0 = fmaf(wa.x, x1[j].x, a0); a0 = fmaf(wa.y, x1[j].y, a0);
        a0 = fmaf(wa.z, x1[j].z, a0); a0 = fmaf(wa.w, x1[j].w, a0);
        a1 = fmaf(wb.x, x1[j].x, a1); a1 = fmaf(wb.y, x1[j].y, a1);
        a1 = fmaf(wb.z, x1[j].z, a1); a1 = fmaf(wb.w, x1[j].w, a1);
    }
    float bi0 = 0.f, bi1 = 0.f;
    if (t == 0) { bi0 = v_b[r2]; bi1 = v_b[r2 + 1]; }   // overlaps reduce
    a0 = wave_red(a0); a1 = wave_red(a1);
    if (lane == 0) { red[wid] = a0; red[8 + wid] = a1; }
    __syncthreads();                       // WAR guard: S1 reads of A/B done
    if (t == 0) {
        vvec[r2]     = red[0] + red[1] + red[2] + red[3] + bi0;
        vvec[r2 + 1] = red[8] + red[9] + red[10] + red[11] + bi1;
    }
    barrier_arrive(flags, b);

    // ---- W2 -> A, W3 -> B: in flight during the bar1 spin ----
    stage8k(wv + (size_t)r2 * ED,         sA,        wid, lane);
    stage8k(wv + (size_t)(r2 + 1) * ED,   sA + 2048, wid, lane);
    stage8k(mo_w + (size_t)r2 * ED,       sB,        wid, lane);
    stage8k(mo_w + (size_t)(r2 + 1) * ED, sB + 2048, wid, lane);

    barrier_wait(flags);                   // syncthreads drains vmcnt

    // ---- stage 2: ctx = wv @ v + bv (weights in LDS slot A) ----
    const float4* x2p = (const float4*)vvec;
    float4 x2[2];
#pragma unroll
    for (int j = 0; j < 2; ++j) x2[j] = x2p[t + j * NT];
    a0 = 0.f; a1 = 0.f;
#pragma unroll
    for (int j = 0; j < 2; ++j) {
        float4 wa = A4[t + j * NT], wb = A4[512 + t + j * NT];
        a0 = fmaf(wa.x, x2[j].x, a0); a0 = fmaf(wa.y, x2[j].y, a0);
        a0 = fmaf(wa.z, x2[j].z, a0); a0 = fmaf(wa.w, x2[j].w, a0);
        a1 = fmaf(wb.x, x2[j].x, a1); a1 = fmaf(wb.y, x2[j].y, a1);
        a1 = fmaf(wb.z, x2[j].z, a1); a1 = fmaf(wb.w, x2[j].w, a1);
    }
    if (t == 0) { bi0 = bv[r2]; bi1 = bv[r2 + 1]; }
    a0 = wave_red(a0); a1 = wave_red(a1);
    if (lane == 0) { red[wid] = a0; red[8 + wid] = a1; }
    __syncthreads();                       // WAR guard: S2 reads of A done
    if (t == 0) {
        ctx[r2]     = red[0] + red[1] + red[2] + red[3] + bi0;
        ctx[r2 + 1] = red[8] + red[9] + red[10] + red[11] + bi1;
    }
    barrier_arrive(flags + 64, b);

    // ---- W4 rows r4, r4+1 -> A: in flight during the bar2 spin ----
    stage8k(o_w + (size_t)r4 * ED,       sA,        wid, lane);
    stage8k(o_w + (size_t)(r4 + 1) * ED, sA + 2048, wid, lane);

    barrier_wait(flags + 64);

    // ---- stage 3: attn = mo_w @ ctx + mo_b (weights in LDS slot B) ----
    const float4* x3p = (const float4*)ctx;
    float4 x3[2];
#pragma unroll
    for (int j = 0; j < 2; ++j) x3[j] = x3p[t + j * NT];
    a0 = 0.f; a1 = 0.f;
#pragma unroll
    for (int j = 0; j < 2; ++j) {
        float4 wa = B4[t + j * NT], wb = B4[512 + t + j * NT];
        a0 = fmaf(wa.x, x3[j].x, a0); a0 = fmaf(wa.y, x3[j].y, a0);
        a0 = fmaf(wa.z, x3[j].z, a0); a0 = fmaf(wa.w, x3[j].w, a0);
        a1 = fmaf(wb.x, x3[j].x, a1); a1 = fmaf(wb.y, x3[j].y, a1);
        a1 = fmaf(wb.z, x3[j].z, a1); a1 = fmaf(wb.w, x3[j].w, a1);
    }
    if (t == 0) { bi0 = mo_b[r2]; bi1 = mo_b[r2 + 1]; }
    a0 = wave_red(a0); a1 = wave_red(a1);
    if (lane == 0) { red[wid] = a0; red[8 + wid] = a1; }
    __syncthreads();                       // WAR guard: S3 reads of B done
    if (t == 0) {
        attn[r2]     = red[0] + red[1] + red[2] + red[3] + bi0;
        attn[r2 + 1] = red[8] + red[9] + red[10] + red[11] + bi1;
    }
    barrier_arrive(flags + 128, b);

    // ---- W4 rows r4+2, r4+3 -> B: in flight during the bar3 spin ----
    stage8k(o_w + (size_t)(r4 + 2) * ED, sB,        wid, lane);
    stage8k(o_w + (size_t)(r4 + 3) * ED, sB + 2048, wid, lane);

    barrier_wait(flags + 128);

    // ---- stage 4: out = visual + o_w @ attn + o_b (4 rows from A+B) ----
    const float4* x4p = (const float4*)attn;
    float4 x4[2];
#pragma unroll
    for (int j = 0; j < 2; ++j) x4[j] = x4p[t + j * NT];
    float c0 = 0.f, c1 = 0.f, c2 = 0.f, c3 = 0.f;
#pragma unroll
    for (int j = 0; j < 2; ++j) {
        float4 wa = A4[t + j * NT], wb = A4[512 + t + j * NT];
        float4 wc = B4[t + j * NT], wd = B4[512 + t + j * NT];
        c0 = fmaf(wa.x, x4[j].x, c0); c0 = fmaf(wa.y, x4[j].y, c0);
        c0 = fmaf(wa.z, x4[j].z, c0); c0 = fmaf(wa.w, x4[j].w, c0);
        c1 = fmaf(wb.x, x4[j].x, c1); c1 = fmaf(wb.y, x4[j].y, c1);
        c1 = fmaf(wb.z, x4[j].z, c1); c1 = fmaf(wb.w, x4[j].w, c1);
        c2 = fmaf(wc.x, x4[j].x, c2); c2 = fmaf(wc.y, x4[j].y, c2);
        c2 = fmaf(wc.z, x4[j].z, c2); c2 = fmaf(wc.w, x4[j].w, c2);
        c3 = fmaf(wd.x, x4[j].x, c3); c3 = fmaf(wd.y, x4[j].y, c3);
        c3 = fmaf(wd.z, x4[j].z, c3); c3 = fmaf(wd.w, x4[j].w, c3);
    }
    float bo0 = 0.f, bo1 = 0.f, bo2 = 0.f, bo3 = 0.f;
    if (t == 0) {
        bo0 = o_b[r4] + visual[r4];
        bo1 = o_b[r4 + 1] + visual[r4 + 1];
        bo2 = o_b[r4 + 2] + visual[r4 + 2];
        bo3 = o_b[r4 + 3] + visual[r4 + 3];
    }
    c0 = wave_red(c0); c1 = wave_red(c1); c2 = wave_red(c2); c3 = wave_red(c3);
    if (lane == 0) {
        red[wid] = c0; red[4 + wid] = c1; red[8 + wid] = c2; red[12 + wid] = c3;
    }
    __syncthreads();
    if (t == 0) {
        out[r4]     = red[0]  + red[1]  + red[2]  + red[3]  + bo0;
        out[r4 + 1] = red[4]  + red[5]  + red[6]  + red[7]  + bo1;
        out[r4 + 2] = red[8]  + red[9]  + red[10] + red[11] + bo2;
        out[r4 + 3] = red[12] + red[13] + red[14] + red[15] + bo3;
    }
}

extern "C" void kernel_launch(void* const* d_in, const int* in_sizes, int n_in,
                              void* d_out, int out_size, void* d_ws, size_t ws_size,
                              hipStream_t stream) {
    (void)in_sizes; (void)n_in; (void)out_size; (void)ws_size;
    const float* visual = (const float*)d_in[0];   // [4096]
    const float* text   = (const float*)d_in[1];   // [4096]
    // d_in[2..5] = q_w, q_b, k_w, k_b -> dead (softmax over single key == 1)
    const float* v_w  = (const float*)d_in[6];     // [2048, 4096]
    const float* v_b  = (const float*)d_in[7];     // [2048]
    const float* in_w = (const float*)d_in[8];     // [6144, 2048]
    const float* in_b = (const float*)d_in[9];     // [6144]
    const float* mo_w = (const float*)d_in[10];    // [2048, 2048]
    const float* mo_b = (const float*)d_in[11];    // [2048]
    const float* o_w  = (const float*)d_in[12];    // [4096, 2048]
    const float* o_b  = (const float*)d_in[13];    // [4096]
    float* out = (float*)d_out;                    // [4096]

    const float* wv = in_w + (size_t)2 * ED * ED;  // in_w rows 4096..6143
    const float* bv = in_b + 2 * ED;

    float* ws   = (float*)d_ws;
    float* vvec = ws;               // [2048]
    float* ctx  = ws + ED;          // [2048]
    float* attn = ws + 2 * ED;      // [2048]
    unsigned* flags = (unsigned*)(ws + 8192);   // 3 stages x 64 uints, 32KB offset

    // Workspace is poisoned between iterations -> barrier state must be zeroed.
    hipMemsetAsync(flags, 0, 3 * 64 * sizeof(unsigned), stream);
    fused_chain<<<NB, NT, 0, stream>>>(visual, text, v_w, v_b, wv, bv,
                                       mo_w, mo_b, o_w, o_b,
                                       vvec, ctx, attn, flags, out);
}

// Round 4
// 174.297 us; speedup vs baseline: 1.2777x; 1.0840x over previous
//
#include <hip/hip_runtime.h>

// Fused single-kernel GEMV chain for the DCE'd MHA (kv_len==1 => softmax==1):
//   v    = v_w  @ text + v_b              (2048 x 4096, 32 MB)
//   ctx  = wv   @ v    + bv               (2048 x 2048, 16 MB)  wv = in_w rows 4096..6143
//   attn = mo_w @ ctx  + mo_b             (2048 x 2048, 16 MB)
//   out  = visual + o_w @ attn + o_b      (4096 x 2048, 32 MB)
//
// Rounds 1-3 post-mortem: three different data paths (serialized VGPR loads,
// pinned VGPR loads, LDS-staged global_load_lds) ALL landed at ~250 us.
// The invariant was the barrier: 32 leaf atomic counters packed into 2 cache
// lines (1024 same-line RMWs serialize at the coherence point, ~30-100 us per
// barrier) plus 1024 pollers hammering ONE release line with uncached loads.
// 3 barriers x coherence-point convoy = the entire 220 us gap.
//
// Round-4 fix: spread the barrier.
//  - leaf arrival counters at 256 B stride (32 lines, parallel channels)
//  - root counter on its own line
//  - fan-out release: root completer writes 32 per-leaf release flags
//    (256 B stride); each block polls ITS OWN leaf's flag (32 pollers/line)
//    with s_sleep(8) cadence.
// Critical path per barrier ~3-4 us, hidden under the 16-32 MB weight
// prefetch already in flight across each barrier (staging issued BEFORE the
// spin; barrier_wait's __syncthreads drains vmcnt afterwards).
//
// Data path (unchanged from round 3, proven correct): LDS ping-pong A/B
// 16 KB slots via global_load_lds (no VGPR destination -> compiler cannot
// sink/serialize it); the reduce __syncthreads doubles as WAR guard.
// Residency: 1024 blocks = 256 CU x 4 (33 KB LDS -> 4 blocks/CU), proven
// co-resident in rounds 1-3 (barriers completed, 3x passed).

#define ED 2048
#define VD 4096
#define NB 1024
#define NT 256

// Barrier region layout (uints): leafCnt[l] @ l*64, rootCnt @ 2048,
// leafRel[l] @ 2112 + l*64.  Region size 4224 uints = 16896 B per barrier.
#define BAR_U 4224

__device__ __forceinline__ float wave_red(float v) {
#pragma unroll
    for (int off = 32; off > 0; off >>= 1) v += __shfl_down(v, off, 64);
    return v;
}

__device__ __forceinline__ void gload_lds16(const float* g, float* l) {
    __builtin_amdgcn_global_load_lds(
        (const __attribute__((address_space(1))) void*)g,
        (__attribute__((address_space(3))) void*)l, 16, 0, 0);
}

// Stage one 16 KB row (4096 floats) into an LDS slot. 16 chunks of 1 KB;
// wave w issues chunks 4w..4w+3. gaddr is per-lane, LDS base wave-uniform.
__device__ __forceinline__ void stage16k(const float* g, float* l, int wid, int lane) {
#pragma unroll
    for (int j = 0; j < 4; ++j) {
        const int c = wid * 4 + j;
        gload_lds16(g + c * 256 + lane * 4, l + c * 256);
    }
}

// Stage one 8 KB row (2048 floats): 8 chunks, wave w issues chunks 2w..2w+1.
__device__ __forceinline__ void stage8k(const float* g, float* l, int wid, int lane) {
#pragma unroll
    for (int j = 0; j < 2; ++j) {
        const int c = wid * 2 + j;
        gload_lds16(g + c * 256 + lane * 4, l + c * 256);
    }
}

__device__ __forceinline__ void barrier_arrive(unsigned* base, int b) {
    if (threadIdx.x == 0) {
        __threadfence();   // release: push vvec/ctx/attn stores to coherence point
        // 32 blocks per leaf; leaf counters on separate 256 B lines.
        if (atomicAdd(base + ((b >> 5) << 6), 1u) == 31u) {
            if (atomicAdd(base + 2048, 1u) == 31u) {   // 32 leaves -> root
                // Fan-out: one store per leaf release line.
#pragma unroll
                for (int l = 0; l < 32; ++l)
                    __hip_atomic_store(base + 2112 + l * 64, 1u,
                                       __ATOMIC_RELAXED, __HIP_MEMORY_SCOPE_SYSTEM);
            }
        }
    }
}

__device__ __forceinline__ void barrier_wait(unsigned* base, int b) {
    if (threadIdx.x == 0) {
        unsigned* rel = base + 2112 + ((b >> 5) << 6);
        int spins = 0;
        while (__hip_atomic_load(rel, __ATOMIC_RELAXED,
                                 __HIP_MEMORY_SCOPE_SYSTEM) == 0u) {
            __builtin_amdgcn_s_sleep(8);      // ~0.2 us between polls
            if (++spins > (1 << 16)) break;   // visible fail, never hang
        }
        __threadfence();   // acquire: L1/L2 inv so x-vector reads are fresh
    }
    __syncthreads();       // also drains vmcnt -> staged LDS data valid
}

__global__ __launch_bounds__(NT, 4)
void fused_chain(const float* __restrict__ visual,
                 const float* __restrict__ text,
                 const float* __restrict__ v_w,  const float* __restrict__ v_b,
                 const float* __restrict__ wv,   const float* __restrict__ bv,
                 const float* __restrict__ mo_w, const float* __restrict__ mo_b,
                 const float* __restrict__ o_w,  const float* __restrict__ o_b,
                 float* __restrict__ vvec, float* __restrict__ ctx,
                 float* __restrict__ attn, unsigned* __restrict__ flags,
                 float* __restrict__ out)
{
    __shared__ __align__(16) float sA[4096];   // 16 KB slot A
    __shared__ __align__(16) float sB[4096];   // 16 KB slot B
    __shared__ float red[16];

    const int t    = threadIdx.x;
    const int b    = blockIdx.x;
    const int lane = t & 63;
    const int wid  = t >> 6;
    const int r2   = 2 * b;   // row pair, stages 1-3
    const int r4   = 4 * b;   // row quad, stage 4

    const float4* A4 = (const float4*)sA;
    const float4* B4 = (const float4*)sB;

    // ---- stage W1 rows -> A,B; x1 -> regs ----
    stage16k(v_w + (size_t)r2 * VD,       sA, wid, lane);
    stage16k(v_w + (size_t)(r2 + 1) * VD, sB, wid, lane);
    const float4* x1p = (const float4*)text;
    float4 x1[4];
#pragma unroll
    for (int j = 0; j < 4; ++j) x1[j] = x1p[t + j * NT];
    __syncthreads();                       // drains vmcnt: LDS + x1 ready

    // ---- stage 1: v = v_w @ text + v_b ----
    float a0 = 0.f, a1 = 0.f;
#pragma unroll
    for (int j = 0; j < 4; ++j) {
        float4 wa = A4[t + j * NT], wb = B4[t + j * NT];
        a0 = fmaf(wa.x, x1[j].x, a0); a0 = fmaf(wa.y, x1[j].y, a0);
        a0 = fmaf(wa.z, x1[j].z, a0); a0 = fmaf(wa.w, x1[j].w, a0);
        a1 = fmaf(wb.x, x1[j].x, a1); a1 = fmaf(wb.y, x1[j].y, a1);
        a1 = fmaf(wb.z, x1[j].z, a1); a1 = fmaf(wb.w, x1[j].w, a1);
    }
    float bi0 = 0.f, bi1 = 0.f;
    if (t == 0) { bi0 = v_b[r2]; bi1 = v_b[r2 + 1]; }   // overlaps reduce
    a0 = wave_red(a0); a1 = wave_red(a1);
    if (lane == 0) { red[wid] = a0; red[8 + wid] = a1; }
    __syncthreads();                       // WAR guard: S1 reads of A/B done
    if (t == 0) {
        vvec[r2]     = red[0] + red[1] + red[2] + red[3] + bi0;
        vvec[r2 + 1] = red[8] + red[9] + red[10] + red[11] + bi1;
    }
    barrier_arrive(flags, b);

    // ---- W2 -> A, W3 -> B: in flight during the bar1 spin ----
    stage8k(wv + (size_t)r2 * ED,         sA,        wid, lane);
    stage8k(wv + (size_t)(r2 + 1) * ED,   sA + 2048, wid, lane);
    stage8k(mo_w + (size_t)r2 * ED,       sB,        wid, lane);
    stage8k(mo_w + (size_t)(r2 + 1) * ED, sB + 2048, wid, lane);

    barrier_wait(flags, b);                // syncthreads drains vmcnt

    // ---- stage 2: ctx = wv @ v + bv (weights in LDS slot A) ----
    const float4* x2p = (const float4*)vvec;
    float4 x2[2];
#pragma unroll
    for (int j = 0; j < 2; ++j) x2[j] = x2p[t + j * NT];
    a0 = 0.f; a1 = 0.f;
#pragma unroll
    for (int j = 0; j < 2; ++j) {
        float4 wa = A4[t + j * NT], wb = A4[512 + t + j * NT];
        a0 = fmaf(wa.x, x2[j].x, a0); a0 = fmaf(wa.y, x2[j].y, a0);
        a0 = fmaf(wa.z, x2[j].z, a0); a0 = fmaf(wa.w, x2[j].w, a0);
        a1 = fmaf(wb.x, x2[j].x, a1); a1 = fmaf(wb.y, x2[j].y, a1);
        a1 = fmaf(wb.z, x2[j].z, a1); a1 = fmaf(wb.w, x2[j].w, a1);
    }
    if (t == 0) { bi0 = bv[r2]; bi1 = bv[r2 + 1]; }
    a0 = wave_red(a0); a1 = wave_red(a1);
    if (lane == 0) { red[wid] = a0; red[8 + wid] = a1; }
    __syncthreads();                       // WAR guard: S2 reads of A done
    if (t == 0) {
        ctx[r2]     = red[0] + red[1] + red[2] + red[3] + bi0;
        ctx[r2 + 1] = red[8] + red[9] + red[10] + red[11] + bi1;
    }
    barrier_arrive(flags + BAR_U, b);

    // ---- W4 rows r4, r4+1 -> A: in flight during the bar2 spin ----
    stage8k(o_w + (size_t)r4 * ED,       sA,        wid, lane);
    stage8k(o_w + (size_t)(r4 + 1) * ED, sA + 2048, wid, lane);

    barrier_wait(flags + BAR_U, b);

    // ---- stage 3: attn = mo_w @ ctx + mo_b (weights in LDS slot B) ----
    const float4* x3p = (const float4*)ctx;
    float4 x3[2];
#pragma unroll
    for (int j = 0; j < 2; ++j) x3[j] = x3p[t + j * NT];
    a0 = 0.f; a1 = 0.f;
#pragma unroll
    for (int j = 0; j < 2; ++j) {
        float4 wa = B4[t + j * NT], wb = B4[512 + t + j * NT];
        a0 = fmaf(wa.x, x3[j].x, a0); a0 = fmaf(wa.y, x3[j].y, a0);
        a0 = fmaf(wa.z, x3[j].z, a0); a0 = fmaf(wa.w, x3[j].w, a0);
        a1 = fmaf(wb.x, x3[j].x, a1); a1 = fmaf(wb.y, x3[j].y, a1);
        a1 = fmaf(wb.z, x3[j].z, a1); a1 = fmaf(wb.w, x3[j].w, a1);
    }
    if (t == 0) { bi0 = mo_b[r2]; bi1 = mo_b[r2 + 1]; }
    a0 = wave_red(a0); a1 = wave_red(a1);
    if (lane == 0) { red[wid] = a0; red[8 + wid] = a1; }
    __syncthreads();                       // WAR guard: S3 reads of B done
    if (t == 0) {
        attn[r2]     = red[0] + red[1] + red[2] + red[3] + bi0;
        attn[r2 + 1] = red[8] + red[9] + red[10] + red[11] + bi1;
    }
    barrier_arrive(flags + 2 * BAR_U, b);

    // ---- W4 rows r4+2, r4+3 -> B: in flight during the bar3 spin ----
    stage8k(o_w + (size_t)(r4 + 2) * ED, sB,        wid, lane);
    stage8k(o_w + (size_t)(r4 + 3) * ED, sB + 2048, wid, lane);

    barrier_wait(flags + 2 * BAR_U, b);

    // ---- stage 4: out = visual + o_w @ attn + o_b (4 rows from A+B) ----
    const float4* x4p = (const float4*)attn;
    float4 x4[2];
#pragma unroll
    for (int j = 0; j < 2; ++j) x4[j] = x4p[t + j * NT];
    float c0 = 0.f, c1 = 0.f, c2 = 0.f, c3 = 0.f;
#pragma unroll
    for (int j = 0; j < 2; ++j) {
        float4 wa = A4[t + j * NT], wb = A4[512 + t + j * NT];
        float4 wc = B4[t + j * NT], wd = B4[512 + t + j * NT];
        c0 = fmaf(wa.x, x4[j].x, c0); c0 = fmaf(wa.y, x4[j].y, c0);
        c0 = fmaf(wa.z, x4[j].z, c0); c0 = fmaf(wa.w, x4[j].w, c0);
        c1 = fmaf(wb.x, x4[j].x, c1); c1 = fmaf(wb.y, x4[j].y, c1);
        c1 = fmaf(wb.z, x4[j].z, c1); c1 = fmaf(wb.w, x4[j].w, c1);
        c2 = fmaf(wc.x, x4[j].x, c2); c2 = fmaf(wc.y, x4[j].y, c2);
        c2 = fmaf(wc.z, x4[j].z, c2); c2 = fmaf(wc.w, x4[j].w, c2);
        c3 = fmaf(wd.x, x4[j].x, c3); c3 = fmaf(wd.y, x4[j].y, c3);
        c3 = fmaf(wd.z, x4[j].z, c3); c3 = fmaf(wd.w, x4[j].w, c3);
    }
    float bo0 = 0.f, bo1 = 0.f, bo2 = 0.f, bo3 = 0.f;
    if (t == 0) {
        bo0 = o_b[r4] + visual[r4];
        bo1 = o_b[r4 + 1] + visual[r4 + 1];
        bo2 = o_b[r4 + 2] + visual[r4 + 2];
        bo3 = o_b[r4 + 3] + visual[r4 + 3];
    }
    c0 = wave_red(c0); c1 = wave_red(c1); c2 = wave_red(c2); c3 = wave_red(c3);
    if (lane == 0) {
        red[wid] = c0; red[4 + wid] = c1; red[8 + wid] = c2; red[12 + wid] = c3;
    }
    __syncthreads();
    if (t == 0) {
        out[r4]     = red[0]  + red[1]  + red[2]  + red[3]  + bo0;
        out[r4 + 1] = red[4]  + red[5]  + red[6]  + red[7]  + bo1;
        out[r4 + 2] = red[8]  + red[9]  + red[10] + red[11] + bo2;
        out[r4 + 3] = red[12] + red[13] + red[14] + red[15] + bo3;
    }
}

extern "C" void kernel_launch(void* const* d_in, const int* in_sizes, int n_in,
                              void* d_out, int out_size, void* d_ws, size_t ws_size,
                              hipStream_t stream) {
    (void)in_sizes; (void)n_in; (void)out_size; (void)ws_size;
    const float* visual = (const float*)d_in[0];   // [4096]
    const float* text   = (const float*)d_in[1];   // [4096]
    // d_in[2..5] = q_w, q_b, k_w, k_b -> dead (softmax over single key == 1)
    const float* v_w  = (const float*)d_in[6];     // [2048, 4096]
    const float* v_b  = (const float*)d_in[7];     // [2048]
    const float* in_w = (const float*)d_in[8];     // [6144, 2048]
    const float* in_b = (const float*)d_in[9];     // [6144]
    const float* mo_w = (const float*)d_in[10];    // [2048, 2048]
    const float* mo_b = (const float*)d_in[11];    // [2048]
    const float* o_w  = (const float*)d_in[12];    // [4096, 2048]
    const float* o_b  = (const float*)d_in[13];    // [4096]
    float* out = (float*)d_out;                    // [4096]

    const float* wv = in_w + (size_t)2 * ED * ED;  // in_w rows 4096..6143
    const float* bv = in_b + 2 * ED;

    float* ws   = (float*)d_ws;
    float* vvec = ws;               // [2048]
    float* ctx  = ws + ED;          // [2048]
    float* attn = ws + 2 * ED;      // [2048]
    unsigned* flags = (unsigned*)(ws + 8192);   // 3 x BAR_U uints @ 32 KB offset

    // Workspace is poisoned between iterations -> barrier state must be zeroed.
    hipMemsetAsync(flags, 0, 3 * BAR_U * sizeof(unsigned), stream);
    fused_chain<<<NB, NT, 0, stream>>>(visual, text, v_w, v_b, wv, bv,
                                       mo_w, mo_b, o_w, o_b,
                                       vvec, ctx, attn, flags, out);
}

// Round 5
// 32.903 us; speedup vs baseline: 6.7687x; 5.2973x over previous
//
#include <hip/hip_runtime.h>

// Fused single-kernel GEMV chain for the DCE'd MHA (kv_len==1 => softmax==1):
//   v    = v_w  @ text + v_b              (2048 x 4096, 32 MB)
//   ctx  = wv   @ v    + bv               (2048 x 2048, 16 MB)  wv = in_w rows 4096..6143
//   attn = mo_w @ ctx  + mo_b             (2048 x 2048, 16 MB)
//   out  = visual + o_w @ attn + o_b      (4096 x 2048, 32 MB)
//
// Rounds 1-4 post-mortem: four different kernels (VGPR loads / pinned loads /
// LDS-DMA staging / spread+fanout barrier) ALL ran 230-250 us at a flat
// ~220 GB/s = 0.5 outstanding lines per CU. The invariant: __threadfence()
// from 1024 blocks x 2 per barrier = 6144 whole-L2 writeback/invalidate ops
// (buffer_wbl2 + buffer_inv) spread across 8 XCD L2s -> every load in the
// kernel runs against a continuously-invalidated L2. The fences WERE the cost.
//
// Round-5 fix: ZERO cache-maintenance ops. Only ~8 KB of inter-stage vectors
// + flags need coherence -> move exactly those to uncached system-scope ops
// (sc0 sc1: execute at the coherence point, bypass L1/L2, nothing to flush):
//  - x-vector writes: t0 relaxed SYSTEM atomic stores + s_waitcnt vmcnt(0)
//    (acked at LLC) BEFORE the arrival RMW -> flag observers see the data.
//  - x-vector reads: relaxed SYSTEM 8-byte atomic loads (4/thread).
//  - flags: R4 spread layout (leaf counters / root / fan-out release at 256 B
//    stride), relaxed SYSTEM RMWs (returned value forces completion order).
// Weights (96 MB, read-only) stay on the normal cached path - read-only data
// needs no coherence and now no invalidates ever touch it.
//
// Data path (rounds 3-4, proven correct): LDS ping-pong A/B 16 KB slots via
// global_load_lds; reduce-__syncthreads doubles as WAR guard; next-stage
// weights staged BEFORE the spin; barrier_wait's __syncthreads drains vmcnt.
// Residency: 1024 blocks = 256 CU x 4 (33 KB LDS), proven in rounds 1-4.

#define ED 2048
#define VD 4096
#define NB 1024
#define NT 256

// Barrier region layout (uints): leafCnt[l] @ l*64, rootCnt @ 2048,
// leafRel[l] @ 2112 + l*64.  Region size 4224 uints = 16896 B per barrier.
#define BAR_U 4224

__device__ __forceinline__ float wave_red(float v) {
#pragma unroll
    for (int off = 32; off > 0; off >>= 1) v += __shfl_down(v, off, 64);
    return v;
}

__device__ __forceinline__ void gload_lds16(const float* g, float* l) {
    __builtin_amdgcn_global_load_lds(
        (const __attribute__((address_space(1))) void*)g,
        (__attribute__((address_space(3))) void*)l, 16, 0, 0);
}

// Stage one 16 KB row (4096 floats): 16 chunks of 1 KB; wave w -> chunks 4w..4w+3.
__device__ __forceinline__ void stage16k(const float* g, float* l, int wid, int lane) {
#pragma unroll
    for (int j = 0; j < 4; ++j) {
        const int c = wid * 4 + j;
        gload_lds16(g + c * 256 + lane * 4, l + c * 256);
    }
}

// Stage one 8 KB row (2048 floats): 8 chunks; wave w -> chunks 2w..2w+1.
__device__ __forceinline__ void stage8k(const float* g, float* l, int wid, int lane) {
#pragma unroll
    for (int j = 0; j < 2; ++j) {
        const int c = wid * 2 + j;
        gload_lds16(g + c * 256 + lane * 4, l + c * 256);
    }
}

// Uncached (coherence-point) scalar store / 8-byte load. No cache maintenance.
__device__ __forceinline__ void store_uc(float* p, float v) {
    union { float f; unsigned u; } c; c.f = v;
    __hip_atomic_store((unsigned*)p, c.u, __ATOMIC_RELAXED,
                       __HIP_MEMORY_SCOPE_SYSTEM);
}
__device__ __forceinline__ float2 load_uc2(const float* p) {
    union { unsigned long long u; float2 f; } c;
    c.u = __hip_atomic_load((const unsigned long long*)p, __ATOMIC_RELAXED,
                            __HIP_MEMORY_SCOPE_SYSTEM);
    return c.f;
}

// Arrival: x-stores already issued (uncached). Wait for their LLC ack, then
// climb the tree. RMW return values force completion ordering at the LLC.
__device__ __forceinline__ void barrier_arrive(unsigned* base, int b) {
    if (threadIdx.x == 0) {
        __asm__ volatile("s_waitcnt vmcnt(0)" ::: "memory");
        if (__hip_atomic_fetch_add(base + ((b >> 5) << 6), 1u,
                __ATOMIC_RELAXED, __HIP_MEMORY_SCOPE_SYSTEM) == 31u) {
            if (__hip_atomic_fetch_add(base + 2048, 1u,
                    __ATOMIC_RELAXED, __HIP_MEMORY_SCOPE_SYSTEM) == 31u) {
#pragma unroll
                for (int l = 0; l < 32; ++l)
                    __hip_atomic_store(base + 2112 + l * 64, 1u,
                                       __ATOMIC_RELAXED, __HIP_MEMORY_SCOPE_SYSTEM);
            }
        }
    }
}

__device__ __forceinline__ void barrier_wait(unsigned* base, int b) {
    if (threadIdx.x == 0) {
        unsigned* rel = base + 2112 + ((b >> 5) << 6);
        int spins = 0;
        while (__hip_atomic_load(rel, __ATOMIC_RELAXED,
                                 __HIP_MEMORY_SCOPE_SYSTEM) == 0u) {
            __builtin_amdgcn_s_sleep(4);      // ~0.1 us cadence
            if (++spins > (1 << 17)) break;   // visible fail, never hang
        }
    }
    __syncthreads();       // releases block; also drains vmcnt for staged LDS
}

__global__ __launch_bounds__(NT, 4)
void fused_chain(const float* __restrict__ visual,
                 const float* __restrict__ text,
                 const float* __restrict__ v_w,  const float* __restrict__ v_b,
                 const float* __restrict__ wv,   const float* __restrict__ bv,
                 const float* __restrict__ mo_w, const float* __restrict__ mo_b,
                 const float* __restrict__ o_w,  const float* __restrict__ o_b,
                 float* __restrict__ vvec, float* __restrict__ ctx,
                 float* __restrict__ attn, unsigned* __restrict__ flags,
                 float* __restrict__ out)
{
    __shared__ __align__(16) float sA[4096];   // 16 KB slot A
    __shared__ __align__(16) float sB[4096];   // 16 KB slot B
    __shared__ float red[16];

    const int t    = threadIdx.x;
    const int b    = blockIdx.x;
    const int lane = t & 63;
    const int wid  = t >> 6;
    const int r2   = 2 * b;   // row pair, stages 1-3
    const int r4   = 4 * b;   // row quad, stage 4

    const float4* A4 = (const float4*)sA;
    const float4* B4 = (const float4*)sB;

    // ---- stage W1 rows -> A,B; x1 (kernel input, cached) -> regs ----
    stage16k(v_w + (size_t)r2 * VD,       sA, wid, lane);
    stage16k(v_w + (size_t)(r2 + 1) * VD, sB, wid, lane);
    const float4* x1p = (const float4*)text;
    float4 x1[4];
#pragma unroll
    for (int j = 0; j < 4; ++j) x1[j] = x1p[t + j * NT];
    __syncthreads();                       // drains vmcnt: LDS + x1 ready

    // ---- stage 1: v = v_w @ text + v_b ----
    float a0 = 0.f, a1 = 0.f;
#pragma unroll
    for (int j = 0; j < 4; ++j) {
        float4 wa = A4[t + j * NT], wb = B4[t + j * NT];
        a0 = fmaf(wa.x, x1[j].x, a0); a0 = fmaf(wa.y, x1[j].y, a0);
        a0 = fmaf(wa.z, x1[j].z, a0); a0 = fmaf(wa.w, x1[j].w, a0);
        a1 = fmaf(wb.x, x1[j].x, a1); a1 = fmaf(wb.y, x1[j].y, a1);
        a1 = fmaf(wb.z, x1[j].z, a1); a1 = fmaf(wb.w, x1[j].w, a1);
    }
    float bi0 = 0.f, bi1 = 0.f;
    if (t == 0) { bi0 = v_b[r2]; bi1 = v_b[r2 + 1]; }   // overlaps reduce
    a0 = wave_red(a0); a1 = wave_red(a1);
    if (lane == 0) { red[wid] = a0; red[8 + wid] = a1; }
    __syncthreads();                       // WAR guard: S1 reads of A/B done
    if (t == 0) {
        store_uc(vvec + r2,     red[0] + red[1] + red[2] + red[3] + bi0);
        store_uc(vvec + r2 + 1, red[8] + red[9] + red[10] + red[11] + bi1);
    }
    barrier_arrive(flags, b);

    // ---- W2 -> A, W3 -> B: in flight during the bar1 spin ----
    stage8k(wv + (size_t)r2 * ED,         sA,        wid, lane);
    stage8k(wv + (size_t)(r2 + 1) * ED,   sA + 2048, wid, lane);
    stage8k(mo_w + (size_t)r2 * ED,       sB,        wid, lane);
    stage8k(mo_w + (size_t)(r2 + 1) * ED, sB + 2048, wid, lane);

    barrier_wait(flags, b);

    // ---- stage 2: ctx = wv @ v + bv (weights in LDS slot A) ----
    float2 xl[2], xh[2];
#pragma unroll
    for (int j = 0; j < 2; ++j) {
        xl[j] = load_uc2(vvec + 4 * (t + j * NT));
        xh[j] = load_uc2(vvec + 4 * (t + j * NT) + 2);
    }
    a0 = 0.f; a1 = 0.f;
#pragma unroll
    for (int j = 0; j < 2; ++j) {
        float4 wa = A4[t + j * NT], wb = A4[512 + t + j * NT];
        a0 = fmaf(wa.x, xl[j].x, a0); a0 = fmaf(wa.y, xl[j].y, a0);
        a0 = fmaf(wa.z, xh[j].x, a0); a0 = fmaf(wa.w, xh[j].y, a0);
        a1 = fmaf(wb.x, xl[j].x, a1); a1 = fmaf(wb.y, xl[j].y, a1);
        a1 = fmaf(wb.z, xh[j].x, a1); a1 = fmaf(wb.w, xh[j].y, a1);
    }
    if (t == 0) { bi0 = bv[r2]; bi1 = bv[r2 + 1]; }
    a0 = wave_red(a0); a1 = wave_red(a1);
    if (lane == 0) { red[wid] = a0; red[8 + wid] = a1; }
    __syncthreads();                       // WAR guard: S2 reads of A done
    if (t == 0) {
        store_uc(ctx + r2,     red[0] + red[1] + red[2] + red[3] + bi0);
        store_uc(ctx + r2 + 1, red[8] + red[9] + red[10] + red[11] + bi1);
    }
    barrier_arrive(flags + BAR_U, b);

    // ---- W4 rows r4, r4+1 -> A: in flight during the bar2 spin ----
    stage8k(o_w + (size_t)r4 * ED,       sA,        wid, lane);
    stage8k(o_w + (size_t)(r4 + 1) * ED, sA + 2048, wid, lane);

    barrier_wait(flags + BAR_U, b);

    // ---- stage 3: attn = mo_w @ ctx + mo_b (weights in LDS slot B) ----
#pragma unroll
    for (int j = 0; j < 2; ++j) {
        xl[j] = load_uc2(ctx + 4 * (t + j * NT));
        xh[j] = load_uc2(ctx + 4 * (t + j * NT) + 2);
    }
    a0 = 0.f; a1 = 0.f;
#pragma unroll
    for (int j = 0; j < 2; ++j) {
        float4 wa = B4[t + j * NT], wb = B4[512 + t + j * NT];
        a0 = fmaf(wa.x, xl[j].x, a0); a0 = fmaf(wa.y, xl[j].y, a0);
        a0 = fmaf(wa.z, xh[j].x, a0); a0 = fmaf(wa.w, xh[j].y, a0);
        a1 = fmaf(wb.x, xl[j].x, a1); a1 = fmaf(wb.y, xl[j].y, a1);
        a1 = fmaf(wb.z, xh[j].x, a1); a1 = fmaf(wb.w, xh[j].y, a1);
    }
    if (t == 0) { bi0 = mo_b[r2]; bi1 = mo_b[r2 + 1]; }
    a0 = wave_red(a0); a1 = wave_red(a1);
    if (lane == 0) { red[wid] = a0; red[8 + wid] = a1; }
    __syncthreads();                       // WAR guard: S3 reads of B done
    if (t == 0) {
        store_uc(attn + r2,     red[0] + red[1] + red[2] + red[3] + bi0);
        store_uc(attn + r2 + 1, red[8] + red[9] + red[10] + red[11] + bi1);
    }
    barrier_arrive(flags + 2 * BAR_U, b);

    // ---- W4 rows r4+2, r4+3 -> B: in flight during the bar3 spin ----
    stage8k(o_w + (size_t)(r4 + 2) * ED, sB,        wid, lane);
    stage8k(o_w + (size_t)(r4 + 3) * ED, sB + 2048, wid, lane);

    barrier_wait(flags + 2 * BAR_U, b);

    // ---- stage 4: out = visual + o_w @ attn + o_b (4 rows from A+B) ----
#pragma unroll
    for (int j = 0; j < 2; ++j) {
        xl[j] = load_uc2(attn + 4 * (t + j * NT));
        xh[j] = load_uc2(attn + 4 * (t + j * NT) + 2);
    }
    float c0 = 0.f, c1 = 0.f, c2 = 0.f, c3 = 0.f;
#pragma unroll
    for (int j = 0; j < 2; ++j) {
        float4 wa = A4[t + j * NT], wb = A4[512 + t + j * NT];
        float4 wc = B4[t + j * NT], wd = B4[512 + t + j * NT];
        c0 = fmaf(wa.x, xl[j].x, c0); c0 = fmaf(wa.y, xl[j].y, c0);
        c0 = fmaf(wa.z, xh[j].x, c0); c0 = fmaf(wa.w, xh[j].y, c0);
        c1 = fmaf(wb.x, xl[j].x, c1); c1 = fmaf(wb.y, xl[j].y, c1);
        c1 = fmaf(wb.z, xh[j].x, c1); c1 = fmaf(wb.w, xh[j].y, c1);
        c2 = fmaf(wc.x, xl[j].x, c2); c2 = fmaf(wc.y, xl[j].y, c2);
        c2 = fmaf(wc.z, xh[j].x, c2); c2 = fmaf(wc.w, xh[j].y, c2);
        c3 = fmaf(wd.x, xl[j].x, c3); c3 = fmaf(wd.y, xl[j].y, c3);
        c3 = fmaf(wd.z, xh[j].x, c3); c3 = fmaf(wd.w, xh[j].y, c3);
    }
    float bo0 = 0.f, bo1 = 0.f, bo2 = 0.f, bo3 = 0.f;
    if (t == 0) {
        bo0 = o_b[r4] + visual[r4];
        bo1 = o_b[r4 + 1] + visual[r4 + 1];
        bo2 = o_b[r4 + 2] + visual[r4 + 2];
        bo3 = o_b[r4 + 3] + visual[r4 + 3];
    }
    c0 = wave_red(c0); c1 = wave_red(c1); c2 = wave_red(c2); c3 = wave_red(c3);
    if (lane == 0) {
        red[wid] = c0; red[4 + wid] = c1; red[8 + wid] = c2; red[12 + wid] = c3;
    }
    __syncthreads();
    if (t == 0) {
        out[r4]     = red[0]  + red[1]  + red[2]  + red[3]  + bo0;
        out[r4 + 1] = red[4]  + red[5]  + red[6]  + red[7]  + bo1;
        out[r4 + 2] = red[8]  + red[9]  + red[10] + red[11] + bo2;
        out[r4 + 3] = red[12] + red[13] + red[14] + red[15] + bo3;
    }
}

extern "C" void kernel_launch(void* const* d_in, const int* in_sizes, int n_in,
                              void* d_out, int out_size, void* d_ws, size_t ws_size,
                              hipStream_t stream) {
    (void)in_sizes; (void)n_in; (void)out_size; (void)ws_size;
    const float* visual = (const float*)d_in[0];   // [4096]
    const float* text   = (const float*)d_in[1];   // [4096]
    // d_in[2..5] = q_w, q_b, k_w, k_b -> dead (softmax over single key == 1)
    const float* v_w  = (const float*)d_in[6];     // [2048, 4096]
    const float* v_b  = (const float*)d_in[7];     // [2048]
    const float* in_w = (const float*)d_in[8];     // [6144, 2048]
    const float* in_b = (const float*)d_in[9];     // [6144]
    const float* mo_w = (const float*)d_in[10];    // [2048, 2048]
    const float* mo_b = (const float*)d_in[11];    // [2048]
    const float* o_w  = (const float*)d_in[12];    // [4096, 2048]
    const float* o_b  = (const float*)d_in[13];    // [4096]
    float* out = (float*)d_out;                    // [4096]

    const float* wv = in_w + (size_t)2 * ED * ED;  // in_w rows 4096..6143
    const float* bv = in_b + 2 * ED;

    float* ws   = (float*)d_ws;
    float* vvec = ws;               // [2048]
    float* ctx  = ws + ED;          // [2048]
    float* attn = ws + 2 * ED;      // [2048]
    unsigned* flags = (unsigned*)(ws + 8192);   // 3 x BAR_U uints @ 32 KB offset

    // Workspace is poisoned between iterations -> barrier state must be zeroed.
    hipMemsetAsync(flags, 0, 3 * BAR_U * sizeof(unsigned), stream);
    fused_chain<<<NB, NT, 0, stream>>>(visual, text, v_w, v_b, wv, bv,
                                       mo_w, mo_b, o_w, o_b,
                                       vvec, ctx, attn, flags, out);
}